// Round 7
// baseline (171.670 us; speedup 1.0000x reference)
//
#include <hip/hip_runtime.h>

static constexpr int Vn = 1024;   // codebook size
static constexpr int Dn = 256;    // code dim
static constexpr int NT = 65536;  // B * TOK

typedef float vfloat4 __attribute__((ext_vector_type(4)));  // native vec for NT stores

// ---------------------------------------------------------------------------
// Kernel 1: G = W * W^T (1024x1024, K=256), fp32, 32x32 tiles, 1024 blocks.
// Also emits Gh = bf16(G) (RNE) and Mg = max|G| (for the coarse-scan error
// bound), plus norms[v] = G[v][v]. fp32 G kept for the exact rescan.
// ---------------------------------------------------------------------------
__global__ __launch_bounds__(256) void gram_kernel(const float* __restrict__ W,
                                                   float* __restrict__ G,
                                                   unsigned short* __restrict__ Gh,
                                                   float* __restrict__ norms,
                                                   unsigned* __restrict__ Mg) {
    __shared__ float As[32][33];  // [k][m], +1 pad
    __shared__ float Bs[32][33];
    const int tid = threadIdx.x;
    const int tx = tid & 15;   // 0..15
    const int ty = tid >> 4;   // 0..15
    const int bm = blockIdx.y * 32;
    const int bn = blockIdx.x * 32;
    float acc[2][2] = {};
    for (int k0 = 0; k0 < Dn; k0 += 32) {
#pragma unroll
        for (int s = 0; s < 4; ++s) {
            const int e = tid + 256 * s;
            const int m = e >> 5;   // 0..31
            const int k = e & 31;   // 128B coalesced per 32 lanes
            As[k][m] = W[(bm + m) * Dn + k0 + k];
            Bs[k][m] = W[(bn + m) * Dn + k0 + k];
        }
        __syncthreads();
#pragma unroll
        for (int kk = 0; kk < 32; ++kk) {
            float a[2], b[2];
#pragma unroll
            for (int u = 0; u < 2; ++u) a[u] = As[kk][ty + 16 * u];
#pragma unroll
            for (int w = 0; w < 2; ++w) b[w] = Bs[kk][tx + 16 * w];
#pragma unroll
            for (int u = 0; u < 2; ++u)
#pragma unroll
                for (int w = 0; w < 2; ++w)
                    acc[u][w] = fmaf(a[u], b[w], acc[u][w]);
        }
        __syncthreads();
    }
    float lmax = 0.0f;
#pragma unroll
    for (int u = 0; u < 2; ++u) {
        const int row = bm + ty + 16 * u;
#pragma unroll
        for (int w = 0; w < 2; ++w) {
            const int col = bn + tx + 16 * w;
            const float val = acc[u][w];
            G[row * Vn + col] = val;
            // RNE f32 -> bf16
            const unsigned b = __float_as_uint(val);
            Gh[row * Vn + col] = (unsigned short)((b + 0x7FFFu + ((b >> 16) & 1u)) >> 16);
            lmax = fmaxf(lmax, fabsf(val));
            if (row == col) norms[row] = val;  // fused diag
        }
    }
    // wave max-reduce, one atomic per wave
#pragma unroll
    for (int off = 32; off >= 1; off >>= 1)
        lmax = fmaxf(lmax, __shfl_xor(lmax, off, 64));
    if ((tid & 63) == 0) atomicMax(Mg, __float_as_uint(lmax));  // positive floats: uint-monotone
}

// ---------------------------------------------------------------------------
// Coarse helpers: u_i/u_j pack two bf16 G values (elements v, v+1).
// ---------------------------------------------------------------------------
__device__ __forceinline__ float coarse2(unsigned u_i, unsigned u_j,
                                         float n0, float n1,
                                         float c0, float c1, float m) {
    const float gi0 = __uint_as_float(u_i << 16);
    const float gi1 = __uint_as_float(u_i & 0xFFFF0000u);
    const float gj0 = __uint_as_float(u_j << 16);
    const float gj1 = __uint_as_float(u_j & 0xFFFF0000u);
    const float s0 = fmaf(c1, gj0, fmaf(c0, gi0, n0));
    const float s1 = fmaf(c1, gj1, fmaf(c0, gi1, n1));
    return fminf(m, fminf(s0, s1));
}

__device__ __forceinline__ void rescan2(unsigned u_i, unsigned u_j,
                                        float n0, float n1,
                                        float c0, float c1, float thresh, int vb,
                                        const float* __restrict__ Gi32,
                                        const float* __restrict__ Gj32,
                                        float& bex, int& bv) {
    const float gi0 = __uint_as_float(u_i << 16);
    const float gi1 = __uint_as_float(u_i & 0xFFFF0000u);
    const float gj0 = __uint_as_float(u_j << 16);
    const float gj1 = __uint_as_float(u_j & 0xFFFF0000u);
    const float s0 = fmaf(c1, gj0, fmaf(c0, gi0, n0));
    const float s1 = fmaf(c1, gj1, fmaf(c0, gi1, n1));
    if (s0 <= thresh) {
        const float ex = fmaf(c1, Gj32[vb], fmaf(c0, Gi32[vb], n0));  // round-1 fmaf order
        if (ex < bex || (ex == bex && vb < bv)) { bex = ex; bv = vb; }
    }
    if (s1 <= thresh) {
        const float ex = fmaf(c1, Gj32[vb + 1], fmaf(c0, Gi32[vb + 1], n1));
        if (ex < bex || (ex == bex && (vb + 1) < bv)) { bex = ex; bv = vb + 1; }
    }
}

// ---------------------------------------------------------------------------
// Kernel 2 (FUSED): bf16 coarse argmin + exact fp32 rescan + output write.
// Block = 32 consecutive tokens. Coarse pass streams Gh rows (2 KB/row; Gh =
// 2 MB -> per-XCD-L2 resident), min-only (no index tracking). Candidates
// within min_c + Mg*2^-6 (4x-safe bound on bf16 rounding of the two G terms)
// are re-evaluated from fp32 G with the round-1 fmaf chain -> exact argmin.
// Phase 2 write-out unchanged from round 6.
// ---------------------------------------------------------------------------
__global__ __launch_bounds__(256) void argmin_write_kernel(const int* __restrict__ seq,
                                                           const int* __restrict__ seq2,
                                                           const float* __restrict__ alpha,
                                                           const float* __restrict__ G,
                                                           const unsigned short* __restrict__ Gh,
                                                           const float* __restrict__ norms,
                                                           const unsigned* __restrict__ Mg,
                                                           const float* __restrict__ W,
                                                           float* __restrict__ out) {
    __shared__ float T[32][129];   // [tok][d half], stride 129 -> <=2-way banks
    __shared__ int bestVs[32];
    const int tid = threadIdx.x;
    const int wave = tid >> 6;
    const int lane = tid & 63;
    const int t0 = blockIdx.x * 32;       // first token of block

    // fp32 norms for this lane's 16 v-slots: v = 8*lane+k (s=0), 512+8*lane+k (s=1)
    float4 nn_r[4];
    {
        const float4* n4 = (const float4*)norms;
        nn_r[0] = n4[2 * lane];
        nn_r[1] = n4[2 * lane + 1];
        nn_r[2] = n4[128 + 2 * lane];
        nn_r[3] = n4[129 + 2 * lane];
    }
    const float a = alpha[0];
    const float c0 = -2.0f * (1.0f - a);
    const float c1 = -2.0f * a;
    const float teps = __uint_as_float(*Mg) * 0.015625f;  // Mg * 2^-6 >= 2*eps_true (4x margin)

    // ---- Phase 1: argmin for this wave's 8 tokens (2x2x2 batching) ---------
    for (int bb = 0; bb < 2; ++bb) {
        const int base_t = t0 + wave * 8 + bb * 4;
        const int base_l = wave * 8 + bb * 4;
        int iv[4], jv[4];
#pragma unroll
        for (int q = 0; q < 4; ++q) { iv[q] = seq[base_t + q]; jv[q] = seq2[base_t + q]; }
#pragma unroll
        for (int pair = 0; pair < 2; ++pair) {
            const int qa = pair * 2, qb = pair * 2 + 1;
            const uint4* GiA = (const uint4*)(Gh + iv[qa] * Vn);
            const uint4* GjA = (const uint4*)(Gh + jv[qa] * Vn);
            const uint4* GiB = (const uint4*)(Gh + iv[qb] * Vn);
            const uint4* GjB = (const uint4*)(Gh + jv[qb] * Vn);
            // 8 x 16B loads in flight (2 tokens x 2 rows x 2 groups)
            uint4 gia[2], gja[2], gib[2], gjb[2];
#pragma unroll
            for (int s = 0; s < 2; ++s) {
                const int e = s * 64 + lane;   // uint4 idx; v = 8e..8e+7
                gia[s] = GiA[e];
                gja[s] = GjA[e];
                gib[s] = GiB[e];
                gjb[s] = GjB[e];
            }
            // coarse min (no index tracking)
            float mA = __builtin_inff(), mB = __builtin_inff();
#pragma unroll
            for (int s = 0; s < 2; ++s) {
                const float4 nlo = nn_r[2 * s], nhi = nn_r[2 * s + 1];
                mA = coarse2(gia[s].x, gja[s].x, nlo.x, nlo.y, c0, c1, mA);
                mA = coarse2(gia[s].y, gja[s].y, nlo.z, nlo.w, c0, c1, mA);
                mA = coarse2(gia[s].z, gja[s].z, nhi.x, nhi.y, c0, c1, mA);
                mA = coarse2(gia[s].w, gja[s].w, nhi.z, nhi.w, c0, c1, mA);
                mB = coarse2(gib[s].x, gjb[s].x, nlo.x, nlo.y, c0, c1, mB);
                mB = coarse2(gib[s].y, gjb[s].y, nlo.z, nlo.w, c0, c1, mB);
                mB = coarse2(gib[s].z, gjb[s].z, nhi.x, nhi.y, c0, c1, mB);
                mB = coarse2(gib[s].w, gjb[s].w, nhi.z, nhi.w, c0, c1, mB);
            }
            // butterfly min-reduce (all lanes get the min)
#pragma unroll
            for (int off = 32; off >= 1; off >>= 1) {
                mA = fminf(mA, __shfl_xor(mA, off, 64));
                mB = fminf(mB, __shfl_xor(mB, off, 64));
            }
            const float thA = mA + teps;
            const float thB = mB + teps;
            // exact rescan over candidates
            const float* Gi32A = G + iv[qa] * Vn;
            const float* Gj32A = G + jv[qa] * Vn;
            const float* Gi32B = G + iv[qb] * Vn;
            const float* Gj32B = G + jv[qb] * Vn;
            float exA = __builtin_inff(), exB = __builtin_inff();
            int vA = 0x7FFFFFFF, vB = 0x7FFFFFFF;
#pragma unroll
            for (int s = 0; s < 2; ++s) {
                const float4 nlo = nn_r[2 * s], nhi = nn_r[2 * s + 1];
                const int vb0 = 512 * s + 8 * lane;
                rescan2(gia[s].x, gja[s].x, nlo.x, nlo.y, c0, c1, thA, vb0 + 0, Gi32A, Gj32A, exA, vA);
                rescan2(gia[s].y, gja[s].y, nlo.z, nlo.w, c0, c1, thA, vb0 + 2, Gi32A, Gj32A, exA, vA);
                rescan2(gia[s].z, gja[s].z, nhi.x, nhi.y, c0, c1, thA, vb0 + 4, Gi32A, Gj32A, exA, vA);
                rescan2(gia[s].w, gja[s].w, nhi.z, nhi.w, c0, c1, thA, vb0 + 6, Gi32A, Gj32A, exA, vA);
                rescan2(gib[s].x, gjb[s].x, nlo.x, nlo.y, c0, c1, thB, vb0 + 0, Gi32B, Gj32B, exB, vB);
                rescan2(gib[s].y, gjb[s].y, nlo.z, nlo.w, c0, c1, thB, vb0 + 2, Gi32B, Gj32B, exB, vB);
                rescan2(gib[s].z, gjb[s].z, nhi.x, nhi.y, c0, c1, thB, vb0 + 4, Gi32B, Gj32B, exB, vB);
                rescan2(gib[s].w, gjb[s].w, nhi.z, nhi.w, c0, c1, thB, vb0 + 6, Gi32B, Gj32B, exB, vB);
            }
            // lex (exact score, v) reduce = jnp.argmin first-min semantics
#pragma unroll
            for (int off = 32; off >= 1; off >>= 1) {
                const float oa = __shfl_down(exA, off, 64);
                const int   va = __shfl_down(vA, off, 64);
                if (oa < exA || (oa == exA && va < vA)) { exA = oa; vA = va; }
                const float ob = __shfl_down(exB, off, 64);
                const int   vb = __shfl_down(vB, off, 64);
                if (ob < exB || (ob == exB && vb < vB)) { exB = ob; vB = vb; }
            }
            if (lane == 0) {
                bestVs[base_l + qa] = vA;
                bestVs[base_l + qb] = vB;
            }
        }
    }
    __syncthreads();

    // ---- Phase 2: two d-halves of 128; T[32][129] (unchanged, verified) ----
    const int b   = t0 >> 8;
    const int hw0 = t0 & 255;
    float* outb = out + b * 65536 + hw0;
    const int tok = tid >> 3;        // 0..31 (gather mapping)
    const int l8  = tid & 7;
    const int hw4  = (tid & 7) * 4;  // 0..28 (write mapping)
    const int drow = tid >> 3;       // 0..31
#pragma unroll
    for (int half = 0; half < 2; ++half) {
        const int v = bestVs[tok];
        const float4* Wr = (const float4*)(W + v * Dn + half * 128);
#pragma unroll
        for (int p = 0; p < 4; ++p) {
            const int d4 = p * 8 + l8;          // local float4 idx, 0..31
            const float4 w4 = Wr[d4];
            T[tok][d4 * 4 + 0] = w4.x;
            T[tok][d4 * 4 + 1] = w4.y;
            T[tok][d4 * 4 + 2] = w4.z;
            T[tok][d4 * 4 + 3] = w4.w;
        }
        __syncthreads();
#pragma unroll
        for (int dp = 0; dp < 128; dp += 32) {
            const int dl = dp + drow;           // local d, 0..127
            const int d = half * 128 + dl;
            vfloat4 o;
            o.x = T[hw4 + 0][dl];
            o.y = T[hw4 + 1][dl];
            o.z = T[hw4 + 2][dl];
            o.w = T[hw4 + 3][dl];
            __builtin_nontemporal_store(o, (vfloat4*)(outb + d * 256 + hw4));
        }
        __syncthreads();
    }
}

// ---------------------------------------------------------------------------
extern "C" void kernel_launch(void* const* d_in, const int* in_sizes, int n_in,
                              void* d_out, int out_size, void* d_ws, size_t ws_size,
                              hipStream_t stream) {
    const int*   seq   = (const int*)d_in[0];    // [256,256] int32
    const int*   seq2  = (const int*)d_in[1];    // [256,256] int32
    const float* alpha = (const float*)d_in[2];  // [1]
    const float* W     = (const float*)d_in[3];  // [1024,256] f32
    float* out = (float*)d_out;                  // [256,256,16,16] f32

    char* ws = (char*)d_ws;
    float*          G     = (float*)(ws);                  // 4 MB
    float*          norms = (float*)(ws + 4194304);        // 4 KB
    unsigned short* Gh    = (unsigned short*)(ws + 4198400);  // 2 MB bf16
    unsigned*       Mg    = (unsigned*)(ws + 6295552);     // 4 B

    hipMemsetAsync(Mg, 0, 4, stream);
    gram_kernel<<<dim3(32, 32), 256, 0, stream>>>(W, G, Gh, norms, Mg);
    argmin_write_kernel<<<NT / 32, 256, 0, stream>>>(seq, seq2, alpha, G, Gh, norms, Mg, W, out);
}

// Round 8
// 132.447 us; speedup vs baseline: 1.2961x; 1.2961x over previous
//
#include <hip/hip_runtime.h>

static constexpr int Vn = 1024;   // codebook size
static constexpr int Dn = 256;    // code dim
static constexpr int NT = 65536;  // B * TOK

typedef float vfloat4 __attribute__((ext_vector_type(4)));  // native vec for NT stores

// ---------------------------------------------------------------------------
// Kernel 1: G = W * W^T (1024x1024, K=256), fp32, 32x32 tiles, 1024 blocks.
// Emits Gh = bf16(G) (RNE) and norms[v] = G[v][v]. NO atomics (round-7's
// single-address atomicMax serialized the whole grid: 64.9 us, VALUBusy 10%).
// ---------------------------------------------------------------------------
__global__ __launch_bounds__(256) void gram_kernel(const float* __restrict__ W,
                                                   float* __restrict__ G,
                                                   unsigned short* __restrict__ Gh,
                                                   float* __restrict__ norms) {
    __shared__ float As[32][33];  // [k][m], +1 pad
    __shared__ float Bs[32][33];
    const int tid = threadIdx.x;
    const int tx = tid & 15;   // 0..15
    const int ty = tid >> 4;   // 0..15
    const int bm = blockIdx.y * 32;
    const int bn = blockIdx.x * 32;
    float acc[2][2] = {};
    for (int k0 = 0; k0 < Dn; k0 += 32) {
#pragma unroll
        for (int s = 0; s < 4; ++s) {
            const int e = tid + 256 * s;
            const int m = e >> 5;   // 0..31
            const int k = e & 31;   // 128B coalesced per 32 lanes
            As[k][m] = W[(bm + m) * Dn + k0 + k];
            Bs[k][m] = W[(bn + m) * Dn + k0 + k];
        }
        __syncthreads();
#pragma unroll
        for (int kk = 0; kk < 32; ++kk) {
            float a[2], b[2];
#pragma unroll
            for (int u = 0; u < 2; ++u) a[u] = As[kk][ty + 16 * u];
#pragma unroll
            for (int w = 0; w < 2; ++w) b[w] = Bs[kk][tx + 16 * w];
#pragma unroll
            for (int u = 0; u < 2; ++u)
#pragma unroll
                for (int w = 0; w < 2; ++w)
                    acc[u][w] = fmaf(a[u], b[w], acc[u][w]);
        }
        __syncthreads();
    }
#pragma unroll
    for (int u = 0; u < 2; ++u) {
        const int row = bm + ty + 16 * u;
#pragma unroll
        for (int w = 0; w < 2; ++w) {
            const int col = bn + tx + 16 * w;
            const float val = acc[u][w];
            G[row * Vn + col] = val;
            // RNE f32 -> bf16
            const unsigned b = __float_as_uint(val);
            Gh[row * Vn + col] = (unsigned short)((b + 0x7FFFu + ((b >> 16) & 1u)) >> 16);
            if (row == col) norms[row] = val;  // fused diag
        }
    }
}

// ---------------------------------------------------------------------------
// Coarse helpers: u_i/u_j pack two bf16 G values (elements v, v+1).
// ---------------------------------------------------------------------------
__device__ __forceinline__ float coarse2(unsigned u_i, unsigned u_j,
                                         float n0, float n1,
                                         float c0, float c1, float m) {
    const float gi0 = __uint_as_float(u_i << 16);
    const float gi1 = __uint_as_float(u_i & 0xFFFF0000u);
    const float gj0 = __uint_as_float(u_j << 16);
    const float gj1 = __uint_as_float(u_j & 0xFFFF0000u);
    const float s0 = fmaf(c1, gj0, fmaf(c0, gi0, n0));
    const float s1 = fmaf(c1, gj1, fmaf(c0, gi1, n1));
    return fminf(m, fminf(s0, s1));
}

__device__ __forceinline__ void rescan2(unsigned u_i, unsigned u_j,
                                        float n0, float n1,
                                        float c0, float c1, float thresh, int vb,
                                        const float* __restrict__ Gi32,
                                        const float* __restrict__ Gj32,
                                        float& bex, int& bv) {
    const float gi0 = __uint_as_float(u_i << 16);
    const float gi1 = __uint_as_float(u_i & 0xFFFF0000u);
    const float gj0 = __uint_as_float(u_j << 16);
    const float gj1 = __uint_as_float(u_j & 0xFFFF0000u);
    const float s0 = fmaf(c1, gj0, fmaf(c0, gi0, n0));
    const float s1 = fmaf(c1, gj1, fmaf(c0, gi1, n1));
    if (s0 <= thresh) {
        const float ex = fmaf(c1, Gj32[vb], fmaf(c0, Gi32[vb], n0));  // round-1 fmaf order
        if (ex < bex || (ex == bex && vb < bv)) { bex = ex; bv = vb; }
    }
    if (s1 <= thresh) {
        const float ex = fmaf(c1, Gj32[vb + 1], fmaf(c0, Gi32[vb + 1], n1));
        if (ex < bex || (ex == bex && (vb + 1) < bv)) { bex = ex; bv = vb + 1; }
    }
}

// ---------------------------------------------------------------------------
// Kernel 2 (FUSED): bf16 coarse argmin + exact fp32 rescan + output write.
// Threshold bound: |G[i,j]| <= max_v norms[v] (Cauchy-Schwarz); each wave
// holds all 1024 norms across lanes in nn_r -> teps = wave_max(nn_r)*2^-6,
// computed in-register (no Mg buffer, no atomics, no extra launch).
// ---------------------------------------------------------------------------
__global__ __launch_bounds__(256) void argmin_write_kernel(const int* __restrict__ seq,
                                                           const int* __restrict__ seq2,
                                                           const float* __restrict__ alpha,
                                                           const float* __restrict__ G,
                                                           const unsigned short* __restrict__ Gh,
                                                           const float* __restrict__ norms,
                                                           const float* __restrict__ W,
                                                           float* __restrict__ out) {
    __shared__ float T[32][129];   // [tok][d half], stride 129 -> <=2-way banks
    __shared__ int bestVs[32];
    const int tid = threadIdx.x;
    const int wave = tid >> 6;
    const int lane = tid & 63;
    const int t0 = blockIdx.x * 32;       // first token of block

    // fp32 norms for this lane's 16 v-slots: v = 8*lane+k (s=0), 512+8*lane+k (s=1)
    float4 nn_r[4];
    {
        const float4* n4 = (const float4*)norms;
        nn_r[0] = n4[2 * lane];
        nn_r[1] = n4[2 * lane + 1];
        nn_r[2] = n4[128 + 2 * lane];
        nn_r[3] = n4[129 + 2 * lane];
    }
    // teps = (max_v norms[v]) * 2^-6  >= Mg * 2^-6 >= 2x the coarse error bound
    float wmax;
    {
        float m0 = fmaxf(fmaxf(nn_r[0].x, nn_r[0].y), fmaxf(nn_r[0].z, nn_r[0].w));
        float m1 = fmaxf(fmaxf(nn_r[1].x, nn_r[1].y), fmaxf(nn_r[1].z, nn_r[1].w));
        float m2 = fmaxf(fmaxf(nn_r[2].x, nn_r[2].y), fmaxf(nn_r[2].z, nn_r[2].w));
        float m3 = fmaxf(fmaxf(nn_r[3].x, nn_r[3].y), fmaxf(nn_r[3].z, nn_r[3].w));
        wmax = fmaxf(fmaxf(m0, m1), fmaxf(m2, m3));
#pragma unroll
        for (int off = 32; off >= 1; off >>= 1)
            wmax = fmaxf(wmax, __shfl_xor(wmax, off, 64));
    }
    const float teps = wmax * 0.015625f;

    const float a = alpha[0];
    const float c0 = -2.0f * (1.0f - a);
    const float c1 = -2.0f * a;

    // ---- Phase 1: argmin for this wave's 8 tokens (2x2x2 batching) ---------
    for (int bb = 0; bb < 2; ++bb) {
        const int base_t = t0 + wave * 8 + bb * 4;
        const int base_l = wave * 8 + bb * 4;
        int iv[4], jv[4];
#pragma unroll
        for (int q = 0; q < 4; ++q) { iv[q] = seq[base_t + q]; jv[q] = seq2[base_t + q]; }
#pragma unroll
        for (int pair = 0; pair < 2; ++pair) {
            const int qa = pair * 2, qb = pair * 2 + 1;
            const uint4* GiA = (const uint4*)(Gh + iv[qa] * Vn);
            const uint4* GjA = (const uint4*)(Gh + jv[qa] * Vn);
            const uint4* GiB = (const uint4*)(Gh + iv[qb] * Vn);
            const uint4* GjB = (const uint4*)(Gh + jv[qb] * Vn);
            // 8 x 16B loads in flight (2 tokens x 2 rows x 2 groups)
            uint4 gia[2], gja[2], gib[2], gjb[2];
#pragma unroll
            for (int s = 0; s < 2; ++s) {
                const int e = s * 64 + lane;   // uint4 idx; v = 8e..8e+7
                gia[s] = GiA[e];
                gja[s] = GjA[e];
                gib[s] = GiB[e];
                gjb[s] = GjB[e];
            }
            // coarse min (no index tracking)
            float mA = __builtin_inff(), mB = __builtin_inff();
#pragma unroll
            for (int s = 0; s < 2; ++s) {
                const float4 nlo = nn_r[2 * s], nhi = nn_r[2 * s + 1];
                mA = coarse2(gia[s].x, gja[s].x, nlo.x, nlo.y, c0, c1, mA);
                mA = coarse2(gia[s].y, gja[s].y, nlo.z, nlo.w, c0, c1, mA);
                mA = coarse2(gia[s].z, gja[s].z, nhi.x, nhi.y, c0, c1, mA);
                mA = coarse2(gia[s].w, gja[s].w, nhi.z, nhi.w, c0, c1, mA);
                mB = coarse2(gib[s].x, gjb[s].x, nlo.x, nlo.y, c0, c1, mB);
                mB = coarse2(gib[s].y, gjb[s].y, nlo.z, nlo.w, c0, c1, mB);
                mB = coarse2(gib[s].z, gjb[s].z, nhi.x, nhi.y, c0, c1, mB);
                mB = coarse2(gib[s].w, gjb[s].w, nhi.z, nhi.w, c0, c1, mB);
            }
            // butterfly min-reduce (all lanes get the min)
#pragma unroll
            for (int off = 32; off >= 1; off >>= 1) {
                mA = fminf(mA, __shfl_xor(mA, off, 64));
                mB = fminf(mB, __shfl_xor(mB, off, 64));
            }
            const float thA = mA + teps;
            const float thB = mB + teps;
            // exact rescan over candidates
            const float* Gi32A = G + iv[qa] * Vn;
            const float* Gj32A = G + jv[qa] * Vn;
            const float* Gi32B = G + iv[qb] * Vn;
            const float* Gj32B = G + jv[qb] * Vn;
            float exA = __builtin_inff(), exB = __builtin_inff();
            int vA = 0x7FFFFFFF, vB = 0x7FFFFFFF;
#pragma unroll
            for (int s = 0; s < 2; ++s) {
                const float4 nlo = nn_r[2 * s], nhi = nn_r[2 * s + 1];
                const int vb0 = 512 * s + 8 * lane;
                rescan2(gia[s].x, gja[s].x, nlo.x, nlo.y, c0, c1, thA, vb0 + 0, Gi32A, Gj32A, exA, vA);
                rescan2(gia[s].y, gja[s].y, nlo.z, nlo.w, c0, c1, thA, vb0 + 2, Gi32A, Gj32A, exA, vA);
                rescan2(gia[s].z, gja[s].z, nhi.x, nhi.y, c0, c1, thA, vb0 + 4, Gi32A, Gj32A, exA, vA);
                rescan2(gia[s].w, gja[s].w, nhi.z, nhi.w, c0, c1, thA, vb0 + 6, Gi32A, Gj32A, exA, vA);
                rescan2(gib[s].x, gjb[s].x, nlo.x, nlo.y, c0, c1, thB, vb0 + 0, Gi32B, Gj32B, exB, vB);
                rescan2(gib[s].y, gjb[s].y, nlo.z, nlo.w, c0, c1, thB, vb0 + 2, Gi32B, Gj32B, exB, vB);
                rescan2(gib[s].z, gjb[s].z, nhi.x, nhi.y, c0, c1, thB, vb0 + 4, Gi32B, Gj32B, exB, vB);
                rescan2(gib[s].w, gjb[s].w, nhi.z, nhi.w, c0, c1, thB, vb0 + 6, Gi32B, Gj32B, exB, vB);
            }
            // lex (exact score, v) reduce = jnp.argmin first-min semantics
#pragma unroll
            for (int off = 32; off >= 1; off >>= 1) {
                const float oa = __shfl_down(exA, off, 64);
                const int   va = __shfl_down(vA, off, 64);
                if (oa < exA || (oa == exA && va < vA)) { exA = oa; vA = va; }
                const float ob = __shfl_down(exB, off, 64);
                const int   vb = __shfl_down(vB, off, 64);
                if (ob < exB || (ob == exB && vb < vB)) { exB = ob; vB = vb; }
            }
            if (lane == 0) {
                bestVs[base_l + qa] = vA;
                bestVs[base_l + qb] = vB;
            }
        }
    }
    __syncthreads();

    // ---- Phase 2: two d-halves of 128; T[32][129] (unchanged, verified) ----
    const int b   = t0 >> 8;
    const int hw0 = t0 & 255;
    float* outb = out + b * 65536 + hw0;
    const int tok = tid >> 3;        // 0..31 (gather mapping)
    const int l8  = tid & 7;
    const int hw4  = (tid & 7) * 4;  // 0..28 (write mapping)
    const int drow = tid >> 3;       // 0..31
#pragma unroll
    for (int half = 0; half < 2; ++half) {
        const int v = bestVs[tok];
        const float4* Wr = (const float4*)(W + v * Dn + half * 128);
#pragma unroll
        for (int p = 0; p < 4; ++p) {
            const int d4 = p * 8 + l8;          // local float4 idx, 0..31
            const float4 w4 = Wr[d4];
            T[tok][d4 * 4 + 0] = w4.x;
            T[tok][d4 * 4 + 1] = w4.y;
            T[tok][d4 * 4 + 2] = w4.z;
            T[tok][d4 * 4 + 3] = w4.w;
        }
        __syncthreads();
#pragma unroll
        for (int dp = 0; dp < 128; dp += 32) {
            const int dl = dp + drow;           // local d, 0..127
            const int d = half * 128 + dl;
            vfloat4 o;
            o.x = T[hw4 + 0][dl];
            o.y = T[hw4 + 1][dl];
            o.z = T[hw4 + 2][dl];
            o.w = T[hw4 + 3][dl];
            __builtin_nontemporal_store(o, (vfloat4*)(outb + d * 256 + hw4));
        }
        __syncthreads();
    }
}

// ---------------------------------------------------------------------------
extern "C" void kernel_launch(void* const* d_in, const int* in_sizes, int n_in,
                              void* d_out, int out_size, void* d_ws, size_t ws_size,
                              hipStream_t stream) {
    const int*   seq   = (const int*)d_in[0];    // [256,256] int32
    const int*   seq2  = (const int*)d_in[1];    // [256,256] int32
    const float* alpha = (const float*)d_in[2];  // [1]
    const float* W     = (const float*)d_in[3];  // [1024,256] f32
    float* out = (float*)d_out;                  // [256,256,16,16] f32

    char* ws = (char*)d_ws;
    float*          G     = (float*)(ws);                     // 4 MB
    float*          norms = (float*)(ws + 4194304);           // 4 KB
    unsigned short* Gh    = (unsigned short*)(ws + 4198400);  // 2 MB bf16

    gram_kernel<<<dim3(32, 32), 256, 0, stream>>>(W, G, Gh, norms);
    argmin_write_kernel<<<NT / 32, 256, 0, stream>>>(seq, seq2, alpha, G, Gh, norms, W, out);
}